// Round 12
// baseline (81.249 us; speedup 1.0000x reference)
//
#include <hip/hip_runtime.h>

#define NUM_CLASSES 80
constexpr int Bn = 8;
constexpr int Gn = 128;
constexpr int An = 131072;

constexpr int TB = 256;   // threads per block; ONE anchor per thread

// out layout: cls (B,A,80) | reg (B,A,4) | states (B,A)
constexpr size_t CLS_OFF = 0;
constexpr size_t REG_OFF = (size_t)Bn * An * NUM_CLASSES;
constexpr size_t ST_OFF  = REG_OFF + (size_t)Bn * An * 4;

__global__ __launch_bounds__(TB, 8) void targets_kernel(
    const float* __restrict__ ann,      // (B,G,5) x1,y1,x2,y2,label
    const float* __restrict__ anchors,  // (A,4)
    float* __restrict__ out)
{
#pragma clang fp contract(off)
    const int tid  = threadIdx.x;
    const int b    = blockIdx.y;
    const int base = blockIdx.x * TB;
    const int a    = base + tid;

    __shared__ float4 sbox[Gn];
    __shared__ float  sarea[Gn];
    __shared__ float  slabel[Gn];

    if (tid < Gn) {
        const float* p = ann + ((size_t)b * Gn + tid) * 5;
        const float x1 = p[0], y1 = p[1], x2 = p[2], y2 = p[3];
        sbox[tid]   = make_float4(x1, y1, x2, y2);
        sarea[tid]  = (x2 - x1) * (y2 - y1);   // ref op order
        slabel[tid] = p[4];
    }

    // anchor load issued before the barrier (in flight across it)
    const float4 av = *reinterpret_cast<const float4*>(anchors + (size_t)a * 4);

    __syncthreads();   // staging visible

    const float ax1 = av.x, ay1 = av.y, ax2 = av.z, ay2 = av.w;
    const float wa = ax2 - ax1;
    const float ha = ay2 - ay1;
    const float area_a = wa * ha;        // ref op order

    float interB = -1.0f;                // sentinel: g=0 wins first compare
    float uniB   = 1.0f;
    int   besti  = 0;

    auto g_iter = [&](int g) {
        const float4 bv = sbox[g];       // broadcast ds_read_b128
        const float area_b = sarea[g];   // broadcast ds_read_b32
        float iw = fminf(ax2, bv.z) - fmaxf(ax1, bv.x);
        iw = fmaxf(iw, 0.0f);
        float ih = fminf(ay2, bv.w) - fmaxf(ay1, bv.y);
        ih = fmaxf(ih, 0.0f);
        const float inter = iw * ih;
        const float uni = (area_a + area_b) - inter;   // > 0 here
        // iou_g > iou_best <=> inter*uniB > interB*uni (both unions > 0)
        const bool upd = (inter * uniB) > (interB * uni);
        interB = upd ? inter : interB;
        uniB   = upd ? uni   : uniB;
        besti  = upd ? g     : besti;
    };

    float4* cls_blk = reinterpret_cast<float4*>(
        out + CLS_OFF + ((size_t)b * An + base) * NUM_CLASSES);
    const float4 z = make_float4(0.f, 0.f, 0.f, 0.f);

    // fine-grained interleave: 1 zero-store per 6 g-iters, with a per-block
    // phase prologue so co-resident blocks (and the 2 dispatch passes) stay
    // desynchronized -> store demand per CU is smooth in time.
    const int ph = (blockIdx.x + blockIdx.y) & 7;
    int g = 0;
    for (; g < ph; ++g) g_iter(g);
    for (int i = 0; i < 20; ++i) {
        cls_blk[tid + i * TB] = z;       // data-independent zero-store
        int ge = ph + (i + 1) * 6;
        if (ge > Gn) ge = Gn;
        for (; g < ge; ++g) g_iter(g);
    }
    for (; g < Gn; ++g) g_iter(g);

    const float best = interB / fmaxf(uniB, 1e-8f);   // exact ref-order div
    const float st = (best >= 0.5f) ? 1.0f : ((best < 0.4f) ? 0.0f : -1.0f);
    out[ST_OFF + (size_t)b * An + a] = st;

    {
        const float4 gt = sbox[besti];
        float4 rv;
        rv.x = ((gt.x - ax1) / wa) / 0.2f;
        rv.y = ((gt.y - ay1) / ha) / 0.2f;
        rv.z = ((gt.z - ax2) / wa) / 0.2f;
        rv.w = ((gt.w - ay2) / ha) / 0.2f;
        *reinterpret_cast<float4*>(out + REG_OFF + ((size_t)b * An + a) * 4) = rv;
    }

    const int mylab = (st == 1.0f) ? (int)slabel[besti] : -1;

    // barrier: vmcnt(0) drain orders ALL block zero-stores before patches;
    // each thread then patches its OWN anchor's dword (no slab needed).
    __syncthreads();

    if (mylab >= 0)
        out[CLS_OFF + ((size_t)b * An + a) * NUM_CLASSES + mylab] = 1.0f;
}

extern "C" void kernel_launch(void* const* d_in, const int* in_sizes, int n_in,
                              void* d_out, int out_size, void* d_ws, size_t ws_size,
                              hipStream_t stream) {
    const float* ann     = (const float*)d_in[0];   // (8,128,5)
    const float* anchors = (const float*)d_in[1];   // (131072,4)
    float* out = (float*)d_out;

    dim3 grid(An / TB, Bn, 1);   // 512 x 8 = 4096 blocks (8 resident per CU)
    dim3 block(TB, 1, 1);
    targets_kernel<<<grid, block, 0, stream>>>(ann, anchors, out);
}